// Round 13
// baseline (179.702 us; speedup 1.0000x reference)
//
#include <hip/hip_runtime.h>
#include <math.h>

typedef unsigned long long u64;
typedef unsigned int u32;
typedef unsigned short u16;
typedef unsigned char u8;

#define HH 512
#define WW 512
#define NIMG 96
#define NB 5

__global__ __launch_bounds__(64) void k_zero(int* __restrict__ c) {
    if (threadIdx.x < 32) c[threadIdx.x] = 0;
}

// =======================================================================
// A: sobel + NMS + thresholds -> u64 bitboards. Register-only stencil.
// Lane owns 8 contiguous cols (C0 = lane*8); H/D/M[3][10] in registers,
// literal slot indices via STEP_A/B/C.
// CRITICAL (rounds 10-12 lesson): __launch_bounds__ MUST carry the
// min-waves arg (256,3). Plain (256) makes the backend target ~8 waves/EU
// (~56 VGPR) and spill all 360B of array state to scratch -> 157 MB of
// fake HBM writes. (256,3) caps occupancy at 3 waves/EU -> ~170 VGPR
// budget -> arrays stay resident (round-8-proven regime).
// Output: per-row masks to per-wave LDS slab; band-end 8x8 byte transpose
// (uint4 LDS read + 4 v_perm) -> one u64/plane/lane, coalesced 128B.
// =======================================================================

#define LOADQ(Yp)  do {                                                    \
    int py_ = (Yp); py_ = py_ < 0 ? 0 : (py_ > HH - 1 ? HH - 1 : py_);     \
    const float* rp_ = img + ((size_t)py_ << 9) + C0;                      \
    float4 A_ = *(const float4*)rp_;                                       \
    float4 B_ = *(const float4*)(rp_ + 4);                                 \
    float2 L_ = *(const float2*)(rp_ + (lz ? 0 : -2));                     \
    float2 R_ = *(const float2*)(rp_ + (lw ? 6 : 8));                      \
    q[2] = (int)(A_.x * 255.f); q[3] = (int)(A_.y * 255.f);                \
    q[4] = (int)(A_.z * 255.f); q[5] = (int)(A_.w * 255.f);                \
    q[6] = (int)(B_.x * 255.f); q[7] = (int)(B_.y * 255.f);                \
    q[8] = (int)(B_.z * 255.f); q[9] = (int)(B_.w * 255.f);                \
    int l0_ = (int)(L_.x * 255.f), l1_ = (int)(L_.y * 255.f);              \
    int r0_ = (int)(R_.x * 255.f), r1_ = (int)(R_.y * 255.f);              \
    q[0]  = lz ? q[2] : l0_;  q[1]  = lz ? q[2] : l1_;                     \
    q[10] = lw ? q[9] : r0_;  q[11] = lw ? q[9] : r1_;                     \
  } while (0)

#define DHR(Hs_, Ds_) do {                                                 \
    _Pragma("unroll") for (int i_ = 0; i_ < 10; ++i_) {                    \
      Hs_[i_] = q[i_] + 2 * q[i_ + 1] + q[i_ + 2];                         \
      Ds_[i_] = q[i_ + 2] - q[i_];                                         \
    }                                                                      \
  } while (0)

// mag (10 cols) + 2-bit dir codes (own 8 cols) for row ym_
#define MAGR(ym_, Ha_, Hc_, Da_, Db_, Dc_, Mm_, cd_) do {                  \
    cd_ = 0u;                                                              \
    if ((unsigned)(ym_) < (unsigned)HH) {                                  \
      _Pragma("unroll") for (int i_ = 0; i_ < 10; ++i_) {                  \
        int gx_ = Da_[i_] + 2 * Db_[i_] + Dc_[i_];                         \
        int gy_ = Hc_[i_] - Ha_[i_];                                       \
        int u_ = gx_ < 0 ? -gx_ : gx_;                                     \
        int v_ = gy_ < 0 ? -gy_ : gy_;                                     \
        int mg_ = u_ + v_;                                                 \
        Mm_[i_] = mg_;                                                     \
        if (i_ >= 1 && i_ <= 8) {                                          \
          int a_ = (gy_ < 0) ? -gx_ : gx_;                                 \
          int qv_ = v_ - u_;                                               \
          int t2_ = 2 * u_ * u_;                                           \
          int c_ = (a_ > 0) ? 1 : 3;                                       \
          if (qv_ > 0 && qv_ * qv_ > t2_) c_ = 2;                          \
          if (mg_ * mg_ < t2_) c_ = 0;                                     \
          cd_ |= (u32)c_ << (2 * (i_ - 1));                                \
        }                                                                  \
      }                                                                    \
      if (lz) Mm_[0] = 0;                                                  \
      if (lw) Mm_[9] = 0;                                                  \
    } else {                                                               \
      _Pragma("unroll") for (int i_ = 0; i_ < 10; ++i_) Mm_[i_] = 0;       \
    }                                                                      \
  } while (0)

// classify own 8 cols of row r; write (weak | strong<<8) to wave LDS slab
#define CLASSIFY(Ma_, Mb_, Mc_, cd_, ri_) do {                             \
    u32 eB_ = 0u, sB_ = 0u;                                                \
    _Pragma("unroll") for (int i_ = 1; i_ <= 8; ++i_) {                    \
      int c_ = (int)((cd_ >> (2 * (i_ - 1))) & 3u);                        \
      int m0_ = Mb_[i_];                                                   \
      int n1_ = (c_ == 0) ? Mb_[i_ + 1] : (c_ == 1) ? Mc_[i_ + 1]          \
              : (c_ == 2) ? Mc_[i_]     : Mc_[i_ - 1];                     \
      int n2_ = (c_ == 0) ? Mb_[i_ - 1] : (c_ == 1) ? Ma_[i_ - 1]          \
              : (c_ == 2) ? Ma_[i_]     : Ma_[i_ + 1];                     \
      int nm_ = n1_ > n2_ ? n1_ : n2_;                                     \
      if (m0_ > 50 && m0_ >= nm_) {                                        \
        eB_ |= 1u << (i_ - 1);                                             \
        if (m0_ > 150) sB_ |= 1u << (i_ - 1);                              \
      }                                                                    \
    }                                                                      \
    SB[wv][ri_][lane] = (u16)(eB_ | (sB_ << 8));                           \
  } while (0)

// period-3 rotation, fully literal slot indices (i%3 == 0 / 1 / 2)
#define STEP_A(ii) do { LOADQ(Y0 + (ii) + 2); DHR(H[1], D[1]);             \
    MAGR(Y0 + (ii) + 1, H[2], H[1], D[2], D[0], D[1], M[2], codeNext);     \
    CLASSIFY(M[0], M[1], M[2], codeCur, (ii)); codeCur = codeNext; } while (0)
#define STEP_B(ii) do { LOADQ(Y0 + (ii) + 2); DHR(H[2], D[2]);             \
    MAGR(Y0 + (ii) + 1, H[0], H[2], D[0], D[1], D[2], M[0], codeNext);     \
    CLASSIFY(M[1], M[2], M[0], codeCur, (ii)); codeCur = codeNext; } while (0)
#define STEP_C(ii) do { LOADQ(Y0 + (ii) + 2); DHR(H[0], D[0]);             \
    MAGR(Y0 + (ii) + 1, H[1], H[0], D[1], D[2], D[0], M[1], codeNext);     \
    CLASSIFY(M[2], M[0], M[1], codeCur, (ii)); codeCur = codeNext; } while (0)

__global__ __launch_bounds__(256, 3) void k_sobel_bits(const float* __restrict__ in,
                                                       u64* __restrict__ Wg,
                                                       u64* __restrict__ Eg) {
    __shared__ u16 SB[4][8][72];   // [wave][row][lane], stride 72 for bank spread
    const int tid = threadIdx.x, wv = tid >> 6, lane = tid & 63;
    const int bid = blockIdx.x, z = bid >> 4, q4 = bid & 15;
    const int Y0 = q4 * 32 + wv * 8;          // 8-row band, within one 128-stripe
    const int C0 = lane * 8;                  // 8 contiguous cols per lane
    const float* img = in + ((size_t)z << 18);
    const bool lz = (lane == 0), lw = (lane == 63);

    int H[3][10], D[3][10], M[3][10];
    int q[12];
    u32 codeCur, codeNext, cDump;

    // prologue: DH rows Y0-2,Y0-1,Y0 -> slots 0,1,2 ; mag rows Y0-1,Y0
    LOADQ(Y0 - 2); DHR(H[0], D[0]);
    LOADQ(Y0 - 1); DHR(H[1], D[1]);
    LOADQ(Y0);     DHR(H[2], D[2]);
    MAGR(Y0 - 1, H[0], H[2], D[0], D[1], D[2], M[0], cDump);
    (void)cDump;
    LOADQ(Y0 + 1); DHR(H[0], D[0]);           // row Y0+1 -> slot 0
    MAGR(Y0, H[1], H[0], D[1], D[2], D[0], M[1], codeCur);

    // main sweep, hand-expanded (all slot indices literal -> registers)
    STEP_A(0); STEP_B(1); STEP_C(2);
    STEP_A(3); STEP_B(4); STEP_C(5);
    STEP_A(6); STEP_B(7);

    // epilogue: 8x8 byte transpose (same-wave LDS, no barrier) + wide store
    {
        const int gw = lane >> 3, r = lane & 7;
        const u16* sp = &SB[wv][r][gw << 3];     // 16B-aligned (stride 144B)
        uint4 dd = *(const uint4*)sp;
        u32 wlo = __builtin_amdgcn_perm(dd.y, dd.x, 0x06040200u);
        u32 whi = __builtin_amdgcn_perm(dd.w, dd.z, 0x06040200u);
        u32 slo = __builtin_amdgcn_perm(dd.y, dd.x, 0x07050301u);
        u32 shi = __builtin_amdgcn_perm(dd.w, dd.z, 0x07050301u);
        const int Yr = Y0 + r;
        const size_t wa = (size_t)(z * 16 + (Yr >> 7) * 4 + (gw >> 1)) * 256
                        + (size_t)(Yr & 127) * 2 + (gw & 1);
        Wg[wa] = (u64)wlo | ((u64)whi << 32);
        Eg[wa] = (u64)slo | ((u64)shi << 32);
    }
}

// =================== proven bit-domain hysteresis tail ===================

#define CONVERGE()                                                          \
    for (;;) {                                                              \
        if (tid == 0) s_any = 0;                                            \
        __syncthreads();                                                    \
        for (int slot = tid; slot < 260; slot += 256) {                     \
            int row_ = slot >> 1, w_ = slot & 1;                            \
            u64 E = Eb[row_][w_], Eo = Eb[row_][w_ ^ 1];                    \
            u64 h = E | (E << 1) | (E >> 1);                                \
            if (w_ == 0) h |= (u64)hLE[row_] | ((Eo & 1ull) << 63);         \
            else         h |= (Eo >> 63) | (((u64)hRE[row_]) << 63);        \
            Hb[row_][w_] = h;                                               \
        }                                                                   \
        __syncthreads();                                                    \
        {                                                                   \
            int row_ = (tid >> 1) + 1, w_ = tid & 1;                        \
            u64 W = Wb[row_][w_], E = Eb[row_][w_];                         \
            u64 nb = Hb[row_ - 1][w_] | Hb[row_ + 1][w_] | Hb[row_][w_];    \
            u64 En = E | (W & nb);                                          \
            for (;;) {                                                      \
                u64 E2 = En | (W & ((En << 1) | (En >> 1)));                \
                if (E2 == En) break;                                        \
                En = E2;                                                    \
            }                                                               \
            if (En != E) { Eb[row_][w_] = En; s_any = 1; }                  \
        }                                                                   \
        __syncthreads();                                                    \
        int f_ = s_any;                                                     \
        __syncthreads();                                                    \
        if (!f_) break;                                                     \
    }

#define LOAD_BIT_TILE(LOADW)                                                \
    const int bid = blockIdx.x, z = bid >> 4, t4 = bid & 15;                \
    const int ty = t4 >> 2, tx = t4 & 3;                                    \
    const size_t base = (size_t)bid * 256;                                  \
    const int row = tid >> 1, w = tid & 1;                                  \
    u64 E0 = Eg[base + tid];                                                \
    Eb[row + 1][w] = E0;                                                    \
    if (LOADW) Wb[row + 1][w] = Wg[base + tid];                             \
    if (tid < 128) {                                                        \
        u64 e = 0;                                                          \
        if (tx > 0) e = Eg[base - 256 + (size_t)tid * 2 + 1];               \
        hLE[tid + 1] = (u8)(e >> 63);                                       \
    } else {                                                                \
        int r_ = tid - 128;                                                 \
        u64 e = 0;                                                          \
        if (tx < 3) e = Eg[base + 256 + (size_t)r_ * 2];                    \
        hRE[r_ + 1] = (u8)(e & 1);                                          \
    }                                                                       \
    if (tid < 2) {                                                          \
        u64 e = 0; if (ty > 0) e = Eg[base - 1024 + 254 + tid];             \
        Eb[0][tid] = e;                                                     \
    } else if (tid < 4) {                                                   \
        u64 e = 0; if (ty < 3) e = Eg[base + 1024 + (tid - 2)];             \
        Eb[129][tid - 2] = e;                                               \
    } else if (tid == 4) {                                                  \
        u64 e = 0; if (ty > 0 && tx > 0) e = Eg[base - 1280 + 255];         \
        hLE[0] = (u8)(e >> 63);                                             \
    } else if (tid == 5) {                                                  \
        u64 e = 0; if (ty > 0 && tx < 3) e = Eg[base - 768 + 254];          \
        hRE[0] = (u8)(e & 1);                                               \
    } else if (tid == 6) {                                                  \
        u64 e = 0; if (ty < 3 && tx > 0) e = Eg[base + 768 + 1];            \
        hLE[129] = (u8)(e >> 63);                                           \
    } else if (tid == 7) {                                                  \
        u64 e = 0; if (ty < 3 && tx < 3) e = Eg[base + 1280];               \
        hRE[129] = (u8)(e & 1);                                             \
    }

__global__ __launch_bounds__(256) void k_hystbit(u64* __restrict__ Wg, u64* __restrict__ Eg,
                                                 int* __restrict__ counters, int pass) {
    if (pass > 0 && counters[pass - 1] == 0) return;
    __shared__ u64 Wb[130][2], Eb[130][2], Hb[130][2];
    __shared__ u8 hLE[130], hRE[130];
    __shared__ int s_any, s_chg;
    const int tid = threadIdx.x;
    if (tid == 0) s_chg = 0;

    LOAD_BIT_TILE(1)
    __syncthreads();

    CONVERGE();

    u64 En = Eb[row + 1][w];
    if (En != E0) { Eg[base + tid] = En; s_chg = 1; }
    __syncthreads();
    if (tid == 0 && s_chg) atomicAdd(&counters[pass], 1);
}

__global__ __launch_bounds__(256) void k_hystbit_final(u64* __restrict__ Wg,
                                                       u64* __restrict__ Eg,
                                                       float* __restrict__ outf) {
    __shared__ u64 Wb[130][2], Eb[130][2], Hb[130][2];
    __shared__ u8 hLE[130], hRE[130];
    __shared__ int s_any;
    const int tid = threadIdx.x;

    LOAD_BIT_TILE(1)
    (void)E0;
    __syncthreads();

    CONVERGE();

    const int y0 = ty * 128, x0 = tx * 128;
    float4* op = (float4*)(outf + (size_t)z * (HH * WW));
    const int rg = tid >> 5, cl = tid & 31;
    #pragma unroll
    for (int k = 0; k < 16; ++k) {
        int r = rg + (k << 3);
        u64 E = Eb[r + 1][cl >> 4];
        int b0 = (cl << 2) & 63;
        float4 v;
        v.x = (float)((E >> b0) & 1ull);
        v.y = (float)((E >> (b0 + 1)) & 1ull);
        v.z = (float)((E >> (b0 + 2)) & 1ull);
        v.w = (float)((E >> (b0 + 3)) & 1ull);
        op[((size_t)(y0 + r) * WW + x0 + (cl << 2)) >> 2] = v;
    }
}

extern "C" void kernel_launch(void* const* d_in, const int* in_sizes, int n_in,
                              void* d_out, int out_size, void* d_ws, size_t ws_size,
                              hipStream_t stream) {
    const float* in = (const float*)d_in[0];
    float* out = (float*)d_out;
    int* counters = (int*)d_ws;

    k_zero<<<1, 64, 0, stream>>>(counters);

    const size_t bbwords = (size_t)NIMG * 16 * 128 * 2;   // u64 words per plane
    u64* Wg = (u64*)((char*)d_ws + 256);
    u64* Eg = Wg + bbwords;

    dim3 gA(NIMG * 16);                 // 1536 blocks x 4 waves, 8-row bands
    k_sobel_bits<<<gA, 256, 0, stream>>>(in, Wg, Eg);

    dim3 gB(NIMG * 16);
    for (int p = 0; p < NB; ++p)
        k_hystbit<<<gB, 256, 0, stream>>>(Wg, Eg, counters, p);
    k_hystbit_final<<<gB, 256, 0, stream>>>(Wg, Eg, out);
}

// Round 14
// 109.909 us; speedup vs baseline: 1.6350x; 1.6350x over previous
//
#include <hip/hip_runtime.h>
#include <math.h>

typedef unsigned long long u64;
typedef unsigned int u32;
typedef unsigned short u16;
typedef unsigned char u8;

#define HH 512
#define WW 512
#define NIMG 96
#define NB 5

__global__ __launch_bounds__(64) void k_zero(int* __restrict__ c) {
    if (threadIdx.x < 32) c[threadIdx.x] = 0;
}

// =======================================================================
// A: sobel + NMS + thresholds -> u64 bitboards. Register-only stencil.
// Lane owns 8 contiguous cols (C0 = lane*8).
// ROUNDS 10-13 LESSON: int arr[3][10] state spilled wholesale to scratch
// (400 B/thread -> 157 MB fake HBM writes) no matter what indices or
// launch bounds were used - the allocas never got promoted. Fix: NAMED
// SCALARS via token-pasting macros. Scalars are SSA values; no alloca
// exists, so scratch traffic is structurally impossible.
// Row slots: HD0_/HD1_/HD2_ hold H (=[1,2,1] row sum) and D (=right-left)
// for 3 rows x 10 cols; M0_/M1_/M2_ hold |gx|+|gy| for 3 rows x 10 cols.
// Output: per-row (weak|strong<<8) u16 to per-wave LDS slab; band-end
// 8x8 byte transpose (uint4 read + 4 v_perm) -> one u64/plane/lane,
// coalesced 128B blocks in the proven bitboard layout.
// =======================================================================

#define DECL_HD(P) int P##H0,P##H1,P##H2,P##H3,P##H4,P##H5,P##H6,P##H7,P##H8,P##H9, \
                       P##D0,P##D1,P##D2,P##D3,P##D4,P##D5,P##D6,P##D7,P##D8,P##D9;
#define DECL_M(P)  int P##0,P##1,P##2,P##3,P##4,P##5,P##6,P##7,P##8,P##9;

#define LOADQ(Yp)  do {                                                    \
    int py_ = (Yp); py_ = py_ < 0 ? 0 : (py_ > HH - 1 ? HH - 1 : py_);     \
    const float* rp_ = img + ((size_t)py_ << 9) + C0;                      \
    float4 A_ = *(const float4*)rp_;                                       \
    float4 B_ = *(const float4*)(rp_ + 4);                                 \
    float2 L_ = *(const float2*)(rp_ + (lz ? 0 : -2));                     \
    float2 R_ = *(const float2*)(rp_ + (lw ? 6 : 8));                      \
    q2 = (int)(A_.x * 255.f); q3 = (int)(A_.y * 255.f);                    \
    q4 = (int)(A_.z * 255.f); q5 = (int)(A_.w * 255.f);                    \
    q6 = (int)(B_.x * 255.f); q7 = (int)(B_.y * 255.f);                    \
    q8 = (int)(B_.z * 255.f); q9 = (int)(B_.w * 255.f);                    \
    int l0_ = (int)(L_.x * 255.f), l1_ = (int)(L_.y * 255.f);              \
    int r0_ = (int)(R_.x * 255.f), r1_ = (int)(R_.y * 255.f);              \
    q0  = lz ? q2 : l0_;  q1  = lz ? q2 : l1_;                             \
    q10 = lw ? q9 : r0_;  q11 = lw ? q9 : r1_;                             \
  } while (0)

// H/D for one row (10 cols), fully expanded
#define DHR1(P,i,a,b,c) P##H##i = q##a + 2 * q##b + q##c; P##D##i = q##c - q##a;
#define DHR(P) do {                                                        \
    DHR1(P,0,0,1,2)  DHR1(P,1,1,2,3)  DHR1(P,2,2,3,4)  DHR1(P,3,3,4,5)     \
    DHR1(P,4,4,5,6)  DHR1(P,5,5,6,7)  DHR1(P,6,6,7,8)  DHR1(P,7,7,8,9)     \
    DHR1(P,8,8,9,10) DHR1(P,9,9,10,11)                                     \
  } while (0)

// mag only (halo cols 0 and 9)
#define MAGC(PA,PB,PC,PM,i) {                                              \
    int gx_ = PA##D##i + 2 * PB##D##i + PC##D##i;                          \
    int gy_ = PC##H##i - PA##H##i;                                         \
    int u_ = gx_ < 0 ? -gx_ : gx_;                                         \
    int v_ = gy_ < 0 ? -gy_ : gy_;                                         \
    PM##i = u_ + v_; }

// mag + 2-bit dir code (own cols 1..8)
#define MAGCC(PA,PB,PC,PM,i,sh) {                                          \
    int gx_ = PA##D##i + 2 * PB##D##i + PC##D##i;                          \
    int gy_ = PC##H##i - PA##H##i;                                         \
    int u_ = gx_ < 0 ? -gx_ : gx_;                                         \
    int v_ = gy_ < 0 ? -gy_ : gy_;                                         \
    int mg_ = u_ + v_; PM##i = mg_;                                        \
    int a_ = (gy_ < 0) ? -gx_ : gx_;                                       \
    int qv_ = v_ - u_;                                                     \
    int t2_ = 2 * u_ * u_;                                                 \
    int c_ = (a_ > 0) ? 1 : 3;                                             \
    if (qv_ > 0 && qv_ * qv_ > t2_) c_ = 2;                                \
    if (mg_ * mg_ < t2_) c_ = 0;                                           \
    cdv_ |= (u32)c_ << (sh); }

// PA = row m-1 (H,D), PB = row m (D), PC = row m+1 (H,D); writes PM, cd_
#define MAGR(PA,PB,PC,PM,ym_,cd_) do {                                     \
    u32 cdv_ = 0u;                                                         \
    if ((unsigned)(ym_) < (unsigned)HH) {                                  \
      MAGC(PA,PB,PC,PM,0)                                                  \
      MAGCC(PA,PB,PC,PM,1,0)  MAGCC(PA,PB,PC,PM,2,2)                       \
      MAGCC(PA,PB,PC,PM,3,4)  MAGCC(PA,PB,PC,PM,4,6)                       \
      MAGCC(PA,PB,PC,PM,5,8)  MAGCC(PA,PB,PC,PM,6,10)                      \
      MAGCC(PA,PB,PC,PM,7,12) MAGCC(PA,PB,PC,PM,8,14)                      \
      MAGC(PA,PB,PC,PM,9)                                                  \
      if (lz) PM##0 = 0;                                                   \
      if (lw) PM##9 = 0;                                                   \
    } else {                                                               \
      PM##0 = 0; PM##1 = 0; PM##2 = 0; PM##3 = 0; PM##4 = 0;               \
      PM##5 = 0; PM##6 = 0; PM##7 = 0; PM##8 = 0; PM##9 = 0;               \
    }                                                                      \
    cd_ = cdv_;                                                            \
  } while (0)

// classify one col: im/i/ip literal neighbor names, sh = 2*(bit), bi = bit
#define CLC(MA,MB,MC,im,i,ip,sh,bi) {                                      \
    int c_ = (int)((cdv_ >> (sh)) & 3u);                                   \
    int m0_ = MB##i;                                                       \
    int n1_ = (c_ == 0) ? MB##ip : (c_ == 1) ? MC##ip                      \
            : (c_ == 2) ? MC##i  : MC##im;                                 \
    int n2_ = (c_ == 0) ? MB##im : (c_ == 1) ? MA##im                      \
            : (c_ == 2) ? MA##i  : MA##ip;                                 \
    int nm_ = n1_ > n2_ ? n1_ : n2_;                                       \
    if (m0_ > 50 && m0_ >= nm_) {                                          \
      eB_ |= 1u << (bi);                                                   \
      if (m0_ > 150) sB_ |= 1u << (bi);                                    \
    } }

#define CLASSIFY(MA,MB,MC,cd_,ri_) do {                                    \
    u32 cdv_ = (cd_); u32 eB_ = 0u, sB_ = 0u;                              \
    CLC(MA,MB,MC,0,1,2,0,0)   CLC(MA,MB,MC,1,2,3,2,1)                      \
    CLC(MA,MB,MC,2,3,4,4,2)   CLC(MA,MB,MC,3,4,5,6,3)                      \
    CLC(MA,MB,MC,4,5,6,8,4)   CLC(MA,MB,MC,5,6,7,10,5)                     \
    CLC(MA,MB,MC,6,7,8,12,6)  CLC(MA,MB,MC,7,8,9,14,7)                     \
    SB[wv][ri_][lane] = (u16)(eB_ | (sB_ << 8));                           \
  } while (0)

// period-3 rotation, literal prefixes
#define STEP_A(ii) do { LOADQ(Y0 + (ii) + 2); DHR(HD1_);                   \
    MAGR(HD2_,HD0_,HD1_,M2_, Y0 + (ii) + 1, codeNext);                     \
    CLASSIFY(M0_,M1_,M2_, codeCur, (ii)); codeCur = codeNext; } while (0)
#define STEP_B(ii) do { LOADQ(Y0 + (ii) + 2); DHR(HD2_);                   \
    MAGR(HD0_,HD1_,HD2_,M0_, Y0 + (ii) + 1, codeNext);                     \
    CLASSIFY(M1_,M2_,M0_, codeCur, (ii)); codeCur = codeNext; } while (0)
#define STEP_C(ii) do { LOADQ(Y0 + (ii) + 2); DHR(HD0_);                   \
    MAGR(HD1_,HD2_,HD0_,M1_, Y0 + (ii) + 1, codeNext);                     \
    CLASSIFY(M2_,M0_,M1_, codeCur, (ii)); codeCur = codeNext; } while (0)

__global__ __launch_bounds__(256, 3) void k_sobel_bits(const float* __restrict__ in,
                                                       u64* __restrict__ Wg,
                                                       u64* __restrict__ Eg) {
    __shared__ u16 SB[4][8][72];   // [wave][row][lane], stride 72 for bank spread
    const int tid = threadIdx.x, wv = tid >> 6, lane = tid & 63;
    const int bid = blockIdx.x, z = bid >> 4, tq = bid & 15;
    const int Y0 = tq * 32 + wv * 8;          // 8-row band, within one 128-stripe
    const int C0 = lane * 8;                  // 8 contiguous cols per lane
    const float* img = in + ((size_t)z << 18);
    const bool lz = (lane == 0), lw = (lane == 63);

    DECL_HD(HD0_) DECL_HD(HD1_) DECL_HD(HD2_)
    DECL_M(M0_) DECL_M(M1_) DECL_M(M2_)
    int q0, q1, q2, q3, q4, q5, q6, q7, q8, q9, q10, q11;
    u32 codeCur, codeNext, cDump;

    // prologue: H/D rows Y0-2,Y0-1,Y0 -> HD0,HD1,HD2 ; mag rows Y0-1,Y0
    LOADQ(Y0 - 2); DHR(HD0_);
    LOADQ(Y0 - 1); DHR(HD1_);
    LOADQ(Y0);     DHR(HD2_);
    MAGR(HD0_,HD1_,HD2_,M0_, Y0 - 1, cDump);
    (void)cDump;
    LOADQ(Y0 + 1); DHR(HD0_);                 // row Y0+1 -> HD0
    MAGR(HD1_,HD2_,HD0_,M1_, Y0, codeCur);

    // main sweep, hand-expanded
    STEP_A(0); STEP_B(1); STEP_C(2);
    STEP_A(3); STEP_B(4); STEP_C(5);
    STEP_A(6); STEP_B(7);

    // epilogue: 8x8 byte transpose (same-wave LDS, no barrier) + wide store
    {
        const int gw = lane >> 3, r = lane & 7;
        const u16* sp = &SB[wv][r][gw << 3];     // 16B-aligned (stride 144B)
        uint4 dd = *(const uint4*)sp;
        u32 wlo = __builtin_amdgcn_perm(dd.y, dd.x, 0x06040200u);
        u32 whi = __builtin_amdgcn_perm(dd.w, dd.z, 0x06040200u);
        u32 slo = __builtin_amdgcn_perm(dd.y, dd.x, 0x07050301u);
        u32 shi = __builtin_amdgcn_perm(dd.w, dd.z, 0x07050301u);
        const int Yr = Y0 + r;
        const size_t wa = (size_t)(z * 16 + (Yr >> 7) * 4 + (gw >> 1)) * 256
                        + (size_t)(Yr & 127) * 2 + (gw & 1);
        Wg[wa] = (u64)wlo | ((u64)whi << 32);
        Eg[wa] = (u64)slo | ((u64)shi << 32);
    }
}

// =================== proven bit-domain hysteresis tail ===================

#define CONVERGE()                                                          \
    for (;;) {                                                              \
        if (tid == 0) s_any = 0;                                            \
        __syncthreads();                                                    \
        for (int slot = tid; slot < 260; slot += 256) {                     \
            int row_ = slot >> 1, w_ = slot & 1;                            \
            u64 E = Eb[row_][w_], Eo = Eb[row_][w_ ^ 1];                    \
            u64 h = E | (E << 1) | (E >> 1);                                \
            if (w_ == 0) h |= (u64)hLE[row_] | ((Eo & 1ull) << 63);         \
            else         h |= (Eo >> 63) | (((u64)hRE[row_]) << 63);        \
            Hb[row_][w_] = h;                                               \
        }                                                                   \
        __syncthreads();                                                    \
        {                                                                   \
            int row_ = (tid >> 1) + 1, w_ = tid & 1;                        \
            u64 W = Wb[row_][w_], E = Eb[row_][w_];                         \
            u64 nb = Hb[row_ - 1][w_] | Hb[row_ + 1][w_] | Hb[row_][w_];    \
            u64 En = E | (W & nb);                                          \
            for (;;) {                                                      \
                u64 E2 = En | (W & ((En << 1) | (En >> 1)));                \
                if (E2 == En) break;                                        \
                En = E2;                                                    \
            }                                                               \
            if (En != E) { Eb[row_][w_] = En; s_any = 1; }                  \
        }                                                                   \
        __syncthreads();                                                    \
        int f_ = s_any;                                                     \
        __syncthreads();                                                    \
        if (!f_) break;                                                     \
    }

#define LOAD_BIT_TILE(LOADW)                                                \
    const int bid = blockIdx.x, z = bid >> 4, t4 = bid & 15;                \
    const int ty = t4 >> 2, tx = t4 & 3;                                    \
    const size_t base = (size_t)bid * 256;                                  \
    const int row = tid >> 1, w = tid & 1;                                  \
    u64 E0 = Eg[base + tid];                                                \
    Eb[row + 1][w] = E0;                                                    \
    if (LOADW) Wb[row + 1][w] = Wg[base + tid];                             \
    if (tid < 128) {                                                        \
        u64 e = 0;                                                          \
        if (tx > 0) e = Eg[base - 256 + (size_t)tid * 2 + 1];               \
        hLE[tid + 1] = (u8)(e >> 63);                                       \
    } else {                                                                \
        int r_ = tid - 128;                                                 \
        u64 e = 0;                                                          \
        if (tx < 3) e = Eg[base + 256 + (size_t)r_ * 2];                    \
        hRE[r_ + 1] = (u8)(e & 1);                                          \
    }                                                                       \
    if (tid < 2) {                                                          \
        u64 e = 0; if (ty > 0) e = Eg[base - 1024 + 254 + tid];             \
        Eb[0][tid] = e;                                                     \
    } else if (tid < 4) {                                                   \
        u64 e = 0; if (ty < 3) e = Eg[base + 1024 + (tid - 2)];             \
        Eb[129][tid - 2] = e;                                               \
    } else if (tid == 4) {                                                  \
        u64 e = 0; if (ty > 0 && tx > 0) e = Eg[base - 1280 + 255];         \
        hLE[0] = (u8)(e >> 63);                                             \
    } else if (tid == 5) {                                                  \
        u64 e = 0; if (ty > 0 && tx < 3) e = Eg[base - 768 + 254];          \
        hRE[0] = (u8)(e & 1);                                               \
    } else if (tid == 6) {                                                  \
        u64 e = 0; if (ty < 3 && tx > 0) e = Eg[base + 768 + 1];            \
        hLE[129] = (u8)(e >> 63);                                           \
    } else if (tid == 7) {                                                  \
        u64 e = 0; if (ty < 3 && tx < 3) e = Eg[base + 1280];               \
        hRE[129] = (u8)(e & 1);                                             \
    }

__global__ __launch_bounds__(256) void k_hystbit(u64* __restrict__ Wg, u64* __restrict__ Eg,
                                                 int* __restrict__ counters, int pass) {
    if (pass > 0 && counters[pass - 1] == 0) return;
    __shared__ u64 Wb[130][2], Eb[130][2], Hb[130][2];
    __shared__ u8 hLE[130], hRE[130];
    __shared__ int s_any, s_chg;
    const int tid = threadIdx.x;
    if (tid == 0) s_chg = 0;

    LOAD_BIT_TILE(1)
    __syncthreads();

    CONVERGE();

    u64 En = Eb[row + 1][w];
    if (En != E0) { Eg[base + tid] = En; s_chg = 1; }
    __syncthreads();
    if (tid == 0 && s_chg) atomicAdd(&counters[pass], 1);
}

__global__ __launch_bounds__(256) void k_hystbit_final(u64* __restrict__ Wg,
                                                       u64* __restrict__ Eg,
                                                       float* __restrict__ outf) {
    __shared__ u64 Wb[130][2], Eb[130][2], Hb[130][2];
    __shared__ u8 hLE[130], hRE[130];
    __shared__ int s_any;
    const int tid = threadIdx.x;

    LOAD_BIT_TILE(1)
    (void)E0;
    __syncthreads();

    CONVERGE();

    const int y0 = ty * 128, x0 = tx * 128;
    float4* op = (float4*)(outf + (size_t)z * (HH * WW));
    const int rg = tid >> 5, cl = tid & 31;
    #pragma unroll
    for (int k = 0; k < 16; ++k) {
        int r = rg + (k << 3);
        u64 E = Eb[r + 1][cl >> 4];
        int b0 = (cl << 2) & 63;
        float4 v;
        v.x = (float)((E >> b0) & 1ull);
        v.y = (float)((E >> (b0 + 1)) & 1ull);
        v.z = (float)((E >> (b0 + 2)) & 1ull);
        v.w = (float)((E >> (b0 + 3)) & 1ull);
        op[((size_t)(y0 + r) * WW + x0 + (cl << 2)) >> 2] = v;
    }
}

extern "C" void kernel_launch(void* const* d_in, const int* in_sizes, int n_in,
                              void* d_out, int out_size, void* d_ws, size_t ws_size,
                              hipStream_t stream) {
    const float* in = (const float*)d_in[0];
    float* out = (float*)d_out;
    int* counters = (int*)d_ws;

    k_zero<<<1, 64, 0, stream>>>(counters);

    const size_t bbwords = (size_t)NIMG * 16 * 128 * 2;   // u64 words per plane
    u64* Wg = (u64*)((char*)d_ws + 256);
    u64* Eg = Wg + bbwords;

    dim3 gA(NIMG * 16);                 // 1536 blocks x 4 waves, 8-row bands
    k_sobel_bits<<<gA, 256, 0, stream>>>(in, Wg, Eg);

    dim3 gB(NIMG * 16);
    for (int p = 0; p < NB; ++p)
        k_hystbit<<<gB, 256, 0, stream>>>(Wg, Eg, counters, p);
    k_hystbit_final<<<gB, 256, 0, stream>>>(Wg, Eg, out);
}

// Round 15
// 108.004 us; speedup vs baseline: 1.6638x; 1.0176x over previous
//
#include <hip/hip_runtime.h>
#include <math.h>

typedef unsigned long long u64;
typedef unsigned int u32;
typedef unsigned short u16;
typedef unsigned char u8;

#define HH 512
#define WW 512
#define NIMG 96
#define NB 5

__global__ __launch_bounds__(64) void k_zero(int* __restrict__ c) {
    if (threadIdx.x < 32) c[threadIdx.x] = 0;
}

// =======================================================================
// A: sobel + NMS + thresholds -> u64 bitboards. Register-only stencil,
// SOFTWARE-PIPELINED. Lane owns 8 contiguous cols (C0 = lane*8).
// r10-r13 lesson: array state spills wholesale -> named scalars only.
// r14 lesson: LOADQ immediately consumed -> full HBM latency exposed per
// row (104us vs 37us VALU). Fix: TWO q-register sets (qa/qb); each step
// issues next row's loads into the idle set BEFORE computing on the
// current set -> loads fly under ~1150cy of DHR+MAGR+CLASSIFY.
// Squares use __mul24 (operands < 2^24; qv<0 case masked by qv>0 guard).
// Output: per-row (weak|strong<<8) u16 to per-wave LDS slab; band-end
// 8x8 byte transpose -> one u64/plane/lane, coalesced 128B blocks.
// =======================================================================

#define DECL_HD(P) int P##H0,P##H1,P##H2,P##H3,P##H4,P##H5,P##H6,P##H7,P##H8,P##H9, \
                       P##D0,P##D1,P##D2,P##D3,P##D4,P##D5,P##D6,P##D7,P##D8,P##D9;
#define DECL_M(P)  int P##0,P##1,P##2,P##3,P##4,P##5,P##6,P##7,P##8,P##9;
#define DECL_Q(Q)  int Q##0,Q##1,Q##2,Q##3,Q##4,Q##5,Q##6,Q##7,Q##8,Q##9,Q##10,Q##11;

// load 12-pixel strip of row Yp into q-set Q (2x float4 + 2x float2 halo)
#define LOADQ(Q,Yp)  do {                                                  \
    int py_ = (Yp); py_ = py_ < 0 ? 0 : (py_ > HH - 1 ? HH - 1 : py_);     \
    const float* rp_ = img + ((size_t)py_ << 9) + C0;                      \
    float4 A_ = *(const float4*)rp_;                                       \
    float4 B_ = *(const float4*)(rp_ + 4);                                 \
    float2 L_ = *(const float2*)(rp_ + (lz ? 0 : -2));                     \
    float2 R_ = *(const float2*)(rp_ + (lw ? 6 : 8));                      \
    Q##2 = (int)(A_.x * 255.f); Q##3 = (int)(A_.y * 255.f);                \
    Q##4 = (int)(A_.z * 255.f); Q##5 = (int)(A_.w * 255.f);                \
    Q##6 = (int)(B_.x * 255.f); Q##7 = (int)(B_.y * 255.f);                \
    Q##8 = (int)(B_.z * 255.f); Q##9 = (int)(B_.w * 255.f);                \
    int l0_ = (int)(L_.x * 255.f), l1_ = (int)(L_.y * 255.f);              \
    int r0_ = (int)(R_.x * 255.f), r1_ = (int)(R_.y * 255.f);              \
    Q##0  = lz ? Q##2 : l0_;  Q##1  = lz ? Q##2 : l1_;                     \
    Q##10 = lw ? Q##9 : r0_;  Q##11 = lw ? Q##9 : r1_;                     \
  } while (0)

// H/D for one row (10 cols) from q-set Q, fully expanded
#define DHR1(P,Q,i,a,b,c) P##H##i = Q##a + 2 * Q##b + Q##c; P##D##i = Q##c - Q##a;
#define DHR(P,Q) do {                                                      \
    DHR1(P,Q,0,0,1,2)  DHR1(P,Q,1,1,2,3)  DHR1(P,Q,2,2,3,4)                \
    DHR1(P,Q,3,3,4,5)  DHR1(P,Q,4,4,5,6)  DHR1(P,Q,5,5,6,7)                \
    DHR1(P,Q,6,6,7,8)  DHR1(P,Q,7,7,8,9)  DHR1(P,Q,8,8,9,10)               \
    DHR1(P,Q,9,9,10,11)                                                    \
  } while (0)

// mag only (halo cols 0 and 9)
#define MAGC(PA,PB,PC,PM,i) {                                              \
    int gx_ = PA##D##i + 2 * PB##D##i + PC##D##i;                          \
    int gy_ = PC##H##i - PA##H##i;                                         \
    int u_ = gx_ < 0 ? -gx_ : gx_;                                         \
    int v_ = gy_ < 0 ? -gy_ : gy_;                                         \
    PM##i = u_ + v_; }

// mag + 2-bit dir code (own cols 1..8); squares via __mul24 (all < 2^24)
#define MAGCC(PA,PB,PC,PM,i,sh) {                                          \
    int gx_ = PA##D##i + 2 * PB##D##i + PC##D##i;                          \
    int gy_ = PC##H##i - PA##H##i;                                         \
    int u_ = gx_ < 0 ? -gx_ : gx_;                                         \
    int v_ = gy_ < 0 ? -gy_ : gy_;                                         \
    int mg_ = u_ + v_; PM##i = mg_;                                        \
    int a_ = (gy_ < 0) ? -gx_ : gx_;                                       \
    int qv_ = v_ - u_;                                                     \
    int t2_ = 2 * __mul24(u_, u_);                                         \
    int c_ = (a_ > 0) ? 1 : 3;                                             \
    if (qv_ > 0 && __mul24(qv_, qv_) > t2_) c_ = 2;                        \
    if (__mul24(mg_, mg_) < t2_) c_ = 0;                                   \
    cdv_ |= (u32)c_ << (sh); }

// PA = row m-1 (H,D), PB = row m (D), PC = row m+1 (H,D); writes PM, cd_
#define MAGR(PA,PB,PC,PM,ym_,cd_) do {                                     \
    u32 cdv_ = 0u;                                                         \
    if ((unsigned)(ym_) < (unsigned)HH) {                                  \
      MAGC(PA,PB,PC,PM,0)                                                  \
      MAGCC(PA,PB,PC,PM,1,0)  MAGCC(PA,PB,PC,PM,2,2)                       \
      MAGCC(PA,PB,PC,PM,3,4)  MAGCC(PA,PB,PC,PM,4,6)                       \
      MAGCC(PA,PB,PC,PM,5,8)  MAGCC(PA,PB,PC,PM,6,10)                      \
      MAGCC(PA,PB,PC,PM,7,12) MAGCC(PA,PB,PC,PM,8,14)                      \
      MAGC(PA,PB,PC,PM,9)                                                  \
      if (lz) PM##0 = 0;                                                   \
      if (lw) PM##9 = 0;                                                   \
    } else {                                                               \
      PM##0 = 0; PM##1 = 0; PM##2 = 0; PM##3 = 0; PM##4 = 0;               \
      PM##5 = 0; PM##6 = 0; PM##7 = 0; PM##8 = 0; PM##9 = 0;               \
    }                                                                      \
    cd_ = cdv_;                                                            \
  } while (0)

// classify one col: im/i/ip literal neighbor names, sh = 2*(bit), bi = bit
#define CLC(MA,MB,MC,im,i,ip,sh,bi) {                                      \
    int c_ = (int)((cdv_ >> (sh)) & 3u);                                   \
    int m0_ = MB##i;                                                       \
    int n1_ = (c_ == 0) ? MB##ip : (c_ == 1) ? MC##ip                      \
            : (c_ == 2) ? MC##i  : MC##im;                                 \
    int n2_ = (c_ == 0) ? MB##im : (c_ == 1) ? MA##im                      \
            : (c_ == 2) ? MA##i  : MA##ip;                                 \
    int nm_ = n1_ > n2_ ? n1_ : n2_;                                       \
    if (m0_ > 50 && m0_ >= nm_) {                                          \
      eB_ |= 1u << (bi);                                                   \
      if (m0_ > 150) sB_ |= 1u << (bi);                                    \
    } }

#define CLASSIFY(MA,MB,MC,cd_,ri_) do {                                    \
    u32 cdv_ = (cd_); u32 eB_ = 0u, sB_ = 0u;                              \
    CLC(MA,MB,MC,0,1,2,0,0)   CLC(MA,MB,MC,1,2,3,2,1)                      \
    CLC(MA,MB,MC,2,3,4,4,2)   CLC(MA,MB,MC,3,4,5,6,3)                      \
    CLC(MA,MB,MC,4,5,6,8,4)   CLC(MA,MB,MC,5,6,7,10,5)                     \
    CLC(MA,MB,MC,6,7,8,12,6)  CLC(MA,MB,MC,7,8,9,14,7)                     \
    SB[wv][ri_][lane] = (u16)(eB_ | (sB_ << 8));                           \
  } while (0)

// pipelined step: prefetch row into idle q-set, then compute on current set
#define PSTEP(ii,Qpre,Ypre,Qcur,HDs,PA,PB,PC,PM,MA,MB,MC) do {             \
    LOADQ(Qpre, (Ypre));                                                   \
    DHR(HDs, Qcur);                                                        \
    MAGR(PA,PB,PC,PM, Y0 + (ii) + 1, codeNext);                            \
    CLASSIFY(MA,MB,MC, codeCur, (ii)); codeCur = codeNext; } while (0)
#define LSTEP(ii,Qcur,HDs,PA,PB,PC,PM,MA,MB,MC) do {                       \
    DHR(HDs, Qcur);                                                        \
    MAGR(PA,PB,PC,PM, Y0 + (ii) + 1, codeNext);                            \
    CLASSIFY(MA,MB,MC, codeCur, (ii)); codeCur = codeNext; } while (0)

__global__ __launch_bounds__(256, 3) void k_sobel_bits(const float* __restrict__ in,
                                                       u64* __restrict__ Wg,
                                                       u64* __restrict__ Eg) {
    __shared__ u16 SB[4][8][72];   // [wave][row][lane], stride 72 for bank spread
    const int tid = threadIdx.x, wv = tid >> 6, lane = tid & 63;
    const int bid = blockIdx.x, z = bid >> 4, tq = bid & 15;
    const int Y0 = tq * 32 + wv * 8;          // 8-row band, within one 128-stripe
    const int C0 = lane * 8;                  // 8 contiguous cols per lane
    const float* img = in + ((size_t)z << 18);
    const bool lz = (lane == 0), lw = (lane == 63);

    DECL_HD(HD0_) DECL_HD(HD1_) DECL_HD(HD2_)
    DECL_M(M0_) DECL_M(M1_) DECL_M(M2_)
    DECL_Q(qa) DECL_Q(qb)
    u32 codeCur, codeNext, cDump;

    // prologue (pipelined): row Y0+k -> HD slot (k+2)%3, q-set = parity(k)
    LOADQ(qa, Y0 - 2);
    LOADQ(qb, Y0 - 1);
    DHR(HD0_, qa);
    LOADQ(qa, Y0);
    DHR(HD1_, qb);
    LOADQ(qb, Y0 + 1);
    DHR(HD2_, qa);
    MAGR(HD0_,HD1_,HD2_,M0_, Y0 - 1, cDump);
    (void)cDump;
    LOADQ(qa, Y0 + 2);
    DHR(HD0_, qb);
    MAGR(HD1_,HD2_,HD0_,M1_, Y0, codeCur);

    // main sweep (classify rows Y0..Y0+7); prefetch row Y0+i+3 each step
    PSTEP(0, qb, Y0 + 3, qa, HD1_, HD2_,HD0_,HD1_, M2_, M0_,M1_,M2_);
    PSTEP(1, qa, Y0 + 4, qb, HD2_, HD0_,HD1_,HD2_, M0_, M1_,M2_,M0_);
    PSTEP(2, qb, Y0 + 5, qa, HD0_, HD1_,HD2_,HD0_, M1_, M2_,M0_,M1_);
    PSTEP(3, qa, Y0 + 6, qb, HD1_, HD2_,HD0_,HD1_, M2_, M0_,M1_,M2_);
    PSTEP(4, qb, Y0 + 7, qa, HD2_, HD0_,HD1_,HD2_, M0_, M1_,M2_,M0_);
    PSTEP(5, qa, Y0 + 8, qb, HD0_, HD1_,HD2_,HD0_, M1_, M2_,M0_,M1_);
    PSTEP(6, qb, Y0 + 9, qa, HD1_, HD2_,HD0_,HD1_, M2_, M0_,M1_,M2_);
    LSTEP(7,           qb, HD2_, HD0_,HD1_,HD2_, M0_, M1_,M2_,M0_);

    // epilogue: 8x8 byte transpose (same-wave LDS, no barrier) + wide store
    {
        const int gw = lane >> 3, r = lane & 7;
        const u16* sp = &SB[wv][r][gw << 3];     // 16B-aligned (stride 144B)
        uint4 dd = *(const uint4*)sp;
        u32 wlo = __builtin_amdgcn_perm(dd.y, dd.x, 0x06040200u);
        u32 whi = __builtin_amdgcn_perm(dd.w, dd.z, 0x06040200u);
        u32 slo = __builtin_amdgcn_perm(dd.y, dd.x, 0x07050301u);
        u32 shi = __builtin_amdgcn_perm(dd.w, dd.z, 0x07050301u);
        const int Yr = Y0 + r;
        const size_t wa = (size_t)(z * 16 + (Yr >> 7) * 4 + (gw >> 1)) * 256
                        + (size_t)(Yr & 127) * 2 + (gw & 1);
        Wg[wa] = (u64)wlo | ((u64)whi << 32);
        Eg[wa] = (u64)slo | ((u64)shi << 32);
    }
}

// =================== proven bit-domain hysteresis tail ===================

#define CONVERGE()                                                          \
    for (;;) {                                                              \
        if (tid == 0) s_any = 0;                                            \
        __syncthreads();                                                    \
        for (int slot = tid; slot < 260; slot += 256) {                     \
            int row_ = slot >> 1, w_ = slot & 1;                            \
            u64 E = Eb[row_][w_], Eo = Eb[row_][w_ ^ 1];                    \
            u64 h = E | (E << 1) | (E >> 1);                                \
            if (w_ == 0) h |= (u64)hLE[row_] | ((Eo & 1ull) << 63);         \
            else         h |= (Eo >> 63) | (((u64)hRE[row_]) << 63);        \
            Hb[row_][w_] = h;                                               \
        }                                                                   \
        __syncthreads();                                                    \
        {                                                                   \
            int row_ = (tid >> 1) + 1, w_ = tid & 1;                        \
            u64 W = Wb[row_][w_], E = Eb[row_][w_];                         \
            u64 nb = Hb[row_ - 1][w_] | Hb[row_ + 1][w_] | Hb[row_][w_];    \
            u64 En = E | (W & nb);                                          \
            for (;;) {                                                      \
                u64 E2 = En | (W & ((En << 1) | (En >> 1)));                \
                if (E2 == En) break;                                        \
                En = E2;                                                    \
            }                                                               \
            if (En != E) { Eb[row_][w_] = En; s_any = 1; }                  \
        }                                                                   \
        __syncthreads();                                                    \
        int f_ = s_any;                                                     \
        __syncthreads();                                                    \
        if (!f_) break;                                                     \
    }

#define LOAD_BIT_TILE(LOADW)                                                \
    const int bid = blockIdx.x, z = bid >> 4, t4 = bid & 15;                \
    const int ty = t4 >> 2, tx = t4 & 3;                                    \
    const size_t base = (size_t)bid * 256;                                  \
    const int row = tid >> 1, w = tid & 1;                                  \
    u64 E0 = Eg[base + tid];                                                \
    Eb[row + 1][w] = E0;                                                    \
    if (LOADW) Wb[row + 1][w] = Wg[base + tid];                             \
    if (tid < 128) {                                                        \
        u64 e = 0;                                                          \
        if (tx > 0) e = Eg[base - 256 + (size_t)tid * 2 + 1];               \
        hLE[tid + 1] = (u8)(e >> 63);                                       \
    } else {                                                                \
        int r_ = tid - 128;                                                 \
        u64 e = 0;                                                          \
        if (tx < 3) e = Eg[base + 256 + (size_t)r_ * 2];                    \
        hRE[r_ + 1] = (u8)(e & 1);                                          \
    }                                                                       \
    if (tid < 2) {                                                          \
        u64 e = 0; if (ty > 0) e = Eg[base - 1024 + 254 + tid];             \
        Eb[0][tid] = e;                                                     \
    } else if (tid < 4) {                                                   \
        u64 e = 0; if (ty < 3) e = Eg[base + 1024 + (tid - 2)];             \
        Eb[129][tid - 2] = e;                                               \
    } else if (tid == 4) {                                                  \
        u64 e = 0; if (ty > 0 && tx > 0) e = Eg[base - 1280 + 255];         \
        hLE[0] = (u8)(e >> 63);                                             \
    } else if (tid == 5) {                                                  \
        u64 e = 0; if (ty > 0 && tx < 3) e = Eg[base - 768 + 254];          \
        hRE[0] = (u8)(e & 1);                                               \
    } else if (tid == 6) {                                                  \
        u64 e = 0; if (ty < 3 && tx > 0) e = Eg[base + 768 + 1];            \
        hLE[129] = (u8)(e >> 63);                                           \
    } else if (tid == 7) {                                                  \
        u64 e = 0; if (ty < 3 && tx < 3) e = Eg[base + 1280];               \
        hRE[129] = (u8)(e & 1);                                             \
    }

__global__ __launch_bounds__(256) void k_hystbit(u64* __restrict__ Wg, u64* __restrict__ Eg,
                                                 int* __restrict__ counters, int pass) {
    if (pass > 0 && counters[pass - 1] == 0) return;
    __shared__ u64 Wb[130][2], Eb[130][2], Hb[130][2];
    __shared__ u8 hLE[130], hRE[130];
    __shared__ int s_any, s_chg;
    const int tid = threadIdx.x;
    if (tid == 0) s_chg = 0;

    LOAD_BIT_TILE(1)
    __syncthreads();

    CONVERGE();

    u64 En = Eb[row + 1][w];
    if (En != E0) { Eg[base + tid] = En; s_chg = 1; }
    __syncthreads();
    if (tid == 0 && s_chg) atomicAdd(&counters[pass], 1);
}

__global__ __launch_bounds__(256) void k_hystbit_final(u64* __restrict__ Wg,
                                                       u64* __restrict__ Eg,
                                                       float* __restrict__ outf) {
    __shared__ u64 Wb[130][2], Eb[130][2], Hb[130][2];
    __shared__ u8 hLE[130], hRE[130];
    __shared__ int s_any;
    const int tid = threadIdx.x;

    LOAD_BIT_TILE(1)
    (void)E0;
    __syncthreads();

    CONVERGE();

    const int y0 = ty * 128, x0 = tx * 128;
    float4* op = (float4*)(outf + (size_t)z * (HH * WW));
    const int rg = tid >> 5, cl = tid & 31;
    #pragma unroll
    for (int k = 0; k < 16; ++k) {
        int r = rg + (k << 3);
        u64 E = Eb[r + 1][cl >> 4];
        int b0 = (cl << 2) & 63;
        float4 v;
        v.x = (float)((E >> b0) & 1ull);
        v.y = (float)((E >> (b0 + 1)) & 1ull);
        v.z = (float)((E >> (b0 + 2)) & 1ull);
        v.w = (float)((E >> (b0 + 3)) & 1ull);
        op[((size_t)(y0 + r) * WW + x0 + (cl << 2)) >> 2] = v;
    }
}

extern "C" void kernel_launch(void* const* d_in, const int* in_sizes, int n_in,
                              void* d_out, int out_size, void* d_ws, size_t ws_size,
                              hipStream_t stream) {
    const float* in = (const float*)d_in[0];
    float* out = (float*)d_out;
    int* counters = (int*)d_ws;

    k_zero<<<1, 64, 0, stream>>>(counters);

    const size_t bbwords = (size_t)NIMG * 16 * 128 * 2;   // u64 words per plane
    u64* Wg = (u64*)((char*)d_ws + 256);
    u64* Eg = Wg + bbwords;

    dim3 gA(NIMG * 16);                 // 1536 blocks x 4 waves, 8-row bands
    k_sobel_bits<<<gA, 256, 0, stream>>>(in, Wg, Eg);

    dim3 gB(NIMG * 16);
    for (int p = 0; p < NB; ++p)
        k_hystbit<<<gB, 256, 0, stream>>>(Wg, Eg, counters, p);
    k_hystbit_final<<<gB, 256, 0, stream>>>(Wg, Eg, out);
}